// Round 9
// baseline (619.105 us; speedup 1.0000x reference)
//
#include <hip/hip_runtime.h>
#include <cstdint>
#include <cstddef>

#define TSEQ 2048
#define DDIM 1024

typedef _Float16 f16;
typedef _Float16 f16x2 __attribute__((ext_vector_type(2)));
typedef _Float16 f16x4 __attribute__((ext_vector_type(4)));
typedef _Float16 f16x8 __attribute__((ext_vector_type(8)));
typedef float f32x4 __attribute__((ext_vector_type(4)));

// q,k,v live in (b,h,t,d) layout: ((b*16+h)*2048 + t)*64 + d.
// Conv weights for gemm_qk8 live in MFMA-FRAGMENT order:
//   Wf[nb][kt][f=j*2+s][lane][8] : value = W[o=nb*64+j*16+(lane&15)]
//                                         [i=(kt>>4)*64+s*32+(lane>>4)*8+c][tap w=kt&15]
// K-order is (i-block, tap) so 16 consecutive kt share the same x-rows (shifted).
// v_w lives in the analogous fragment order (no tap axis):
//   Wfv[nb][ib][f=j*2+s][lane][8] : value = v_w[o=nb*64+j*16+(lane&15)]
//                                          [i=ib*64+s*32+(lane>>4)*8+c]

__device__ __align__(16) static const unsigned char g_zero16[16] = {};

__device__ __forceinline__ void gload_lds16(const void* g, void* l) {
  __builtin_amdgcn_global_load_lds(
      (const __attribute__((address_space(1))) void*)g,
      (__attribute__((address_space(3))) void*)l, 16, 0, 0);
}

// ------------- fused fp32->fp16 converts (x, p_w) -------------
__global__ void cvt_all(const float* __restrict__ x, const float* __restrict__ pw,
                        f16* __restrict__ xh, f16* __restrict__ pwh) {
  int b = blockIdx.x;
  const float* src; f16* dst; int i;
  if (b < 4096) { src = x;  dst = xh;  i = b * 256 + threadIdx.x; }
  else          { src = pw; dst = pwh; i = (b - 4096) * 256 + threadIdx.x; }
  float4 v = ((const float4*)src)[i];
  f16x4 h = { (f16)v.x, (f16)v.y, (f16)v.z, (f16)v.w };
  ((f16x4*)dst)[i] = h;
}

// ------- v_w (D,D) fp32 -> fragment-ordered Wfv (mirrors Wf minus tap axis) -------
// grid 256 = nb(16) x ib(16); 256 threads, 2 units each (unit = f*64 + lane).
__global__ __launch_bounds__(256) void cvt_vw_frag(const float* __restrict__ vw,
                                                   f16* __restrict__ dst) {
  const int nb = blockIdx.x >> 4, ib = blockIdx.x & 15;
  const int tid = threadIdx.x;
  #pragma unroll
  for (int h = 0; h < 2; h++) {
    const int u = h * 256 + tid;            // 0..511
    const int f = u >> 6, l = u & 63;
    const int j = f >> 1, s = f & 1;
    const int o = nb * 64 + j * 16 + (l & 15);
    const int i0 = ib * 64 + s * 32 + (l >> 4) * 8;
    const float* p = vw + (size_t)o * 1024 + i0;
    float4 a = *(const float4*)p;
    float4 b = *(const float4*)(p + 4);
    f16x8 v = { (f16)a.x, (f16)a.y, (f16)a.z, (f16)a.w,
                (f16)b.x, (f16)b.y, (f16)b.z, (f16)b.w };
    *(f16x8*)(dst + ((size_t)((nb * 16 + ib) * 8 + f)) * 512 + l * 8) = v;
  }
}

// ------- conv weights w[o][i][16] fp32 -> fragment-ordered Wf, coalesced both ends -------
__global__ __launch_bounds__(256) void cvt_w_frag(const float* __restrict__ qw,
                                                  const float* __restrict__ kw,
                                                  f16* __restrict__ qd, f16* __restrict__ kd) {
  extern __shared__ f16 wt_lds[];    // 16*16*130 f16 = 66560 B
  const int bid = blockIdx.x;
  const int proj = bid >> 9;
  const int nb = (bid >> 5) & 15;
  const int j = (bid >> 3) & 3;
  const int ic = bid & 7;
  const float* src = proj ? kw : qw;
  f16* dst = proj ? kd : qd;
  const int o_base = nb * 64 + j * 16;
  const int tid = threadIdx.x;
  const int lane = tid & 63;
  const int wv = tid >> 6;

  #pragma unroll
  for (int p = 0; p < 32; p++) {
    const int gidx = p * 256 + tid;         // 0..8191
    const int o_r = gidx >> 9;              // 0..15
    const int i_r = (gidx >> 2) & 127;      // 0..127
    const int wq2 = gidx & 3;               // w-quad
    float4 v = *(const float4*)(src + (size_t)(o_base + o_r) * 16384 +
                                (size_t)(ic * 128 + i_r) * 16 + wq2 * 4);
    const int g = i_r >> 3;
    const int gp = (g & 8) | ((g & 7) ^ (o_r & 7));
    const int ip = gp * 8 + (i_r & 7);
    f16* t0 = wt_lds + ((wq2 * 4) * 16 + o_r) * 130 + ip;
    t0[0]    = (f16)v.x;
    t0[2080] = (f16)v.y;
    t0[4160] = (f16)v.z;
    t0[6240] = (f16)v.w;
  }
  __syncthreads();

  const int o = lane & 15;
  const int lhi = lane >> 4;
  #pragma unroll
  for (int u4 = 0; u4 < 16; u4++) {
    const int u = u4 * 4 + wv;              // 0..63
    const int w = u >> 2, ih = (u >> 1) & 1, s = u & 1;
    const int gl = ih * 8 + s * 4 + lhi;    // linear granule 0..15
    const int gp = (gl & 8) | ((gl & 7) ^ (o & 7));
    f16x8 val = *(const f16x8*)&wt_lds[(w * 16 + o) * 130 + gp * 8];
    const size_t unit = ((size_t)(nb * 256 + (ic * 2 + ih) * 16 + w) * 8) + j * 2 + s;
    *(f16x8*)(dst + unit * 512 + lane * 8) = val;
  }
}

// ------------- fused q+k+v GEMM: A-slab in LDS, B direct global->VGPR -------------
// EXACT round-3 body (known 211 us) + v-projection fused: v's A-fragments for output
// row r are x[t0+r] = the tap wt=15 fragments the conv sweep already reads (srcT =
// t0+row+15-15). At each i-block's last tap, wp==0 waves run 32 extra MFMA against
// Wfv fragments, accumulating v's K=1024 across the 16 i-blocks. +6% MFMA on half
// the waves; kills the separate v-proj GEMM launch and its 10.5MB of re-reads.
__global__ __launch_bounds__(512, 1) void gemm_qk8(
    const f16* __restrict__ xh,
    const f16* __restrict__ Wfq, const f16* __restrict__ Wfk, const f16* __restrict__ Wfv,
    const float* __restrict__ bq, const float* __restrict__ bk, const float* __restrict__ bv,
    f16* __restrict__ oq, f16* __restrict__ ok, f16* __restrict__ ov)
{
  extern __shared__ __align__(16) f16 smem[];   // 2 * 17408 f16 = 68 KB
  const int tid = threadIdx.x;
  const int lane = tid & 63;
  const int wid = tid >> 6;          // 0..7
  const int wq = wid >> 1;           // M-quarter 0..3 (64 rows each)
  const int wp = wid & 1;            // 0 = q projection (+v), 1 = k projection

  // XCD-bijective remap: each XCD owns 2 n-columns (weights fetched once per XCD)
  const int flat = blockIdx.y * 16 + blockIdx.x;
  const int xcd = flat & 7;
  const int idx = flat >> 3;                  // 0..31
  const int nblk = xcd * 2 + (idx >> 4);
  const int mblk = idx & 15;
  const int m0 = mblk * 256;
  const int n0 = nblk * 64;
  const int bT = m0 & ~(TSEQ - 1);
  const int t0 = m0 & (TSEQ - 1);

  // staging swizzle: lane l writes LDS slot (l&7); global chunk = (l&7)^(row&7)
  const int srow = lane >> 3;
  const int chunk8 = (((lane & 7) ^ (srow & 7)) << 3);

  const f16* Wf = wp ? Wfk : Wfq;
  const f16* wbase = Wf + ((size_t)nblk << 20) + lane * 8;   // nblk * 1048576 f16
  const f16* vbase = Wfv + ((size_t)nblk << 16) + lane * 8;  // nblk * 65536 f16

  f32x4 acc[4][4] = {};
  f32x4 vacc[4][4] = {};
  f16x8 bfr[2][8];
  f16x8 afr[2][8];
  f16x8 vf[8];

  // stage the 271-row x 64-channel slab for i-block ib2 (34 groups of 8 rows)
  auto stageX = [&](int ib2, int bufp) {
    f16* sb = smem + bufp * 17408;
    const int ic = ib2 * 64 + chunk8;
    #pragma unroll
    for (int c = 0; c < 5; c++) {
      const int g = c * 8 + wid;
      if (g < 34) {
        const int srcT = t0 + g * 8 + srow - 15;
        const void* gp = (srcT >= 0)
            ? (const void*)(xh + (((size_t)(bT + srcT)) << 10) + ic)
            : (const void*)g_zero16;
        gload_lds16(gp, (void*)&sb[g * 512]);
      }
    }
  };

  auto loadB = [&](int kt, f16x8* bf) {
    const f16* p = wbase + ((size_t)kt << 12);   // kt * 4096 f16
    #pragma unroll
    for (int f = 0; f < 8; f++)
      bf[f] = *(const f16x8*)(p + f * 512);
  };

  auto loadV = [&](int ib2, f16x8* bf) {
    const f16* p = vbase + ((size_t)ib2 << 12);  // ib * 4096 f16
    #pragma unroll
    for (int f = 0; f < 8; f++)
      bf[f] = *(const f16x8*)(p + f * 512);
  };

  auto readA = [&](const f16* xb, int wt, f16x8* af) {
    const int rx = ((lane & 7) + wt) & 7;
    const int sl0 = (((lane >> 4)) ^ rx) << 3;
    const int sl1 = (((lane >> 4) + 4) ^ rx) << 3;
    #pragma unroll
    for (int i = 0; i < 4; i++) {
      const int row = wq * 64 + i * 16 + (lane & 15) + wt;
      af[i]     = *(const f16x8*)&xb[row * 64 + sl0];
      af[4 + i] = *(const f16x8*)&xb[row * 64 + sl1];
    }
  };

  // prologue
  stageX(0, 0);
  loadB(0, bfr[0]);
  asm volatile("s_waitcnt vmcnt(0)" ::: "memory");
  __builtin_amdgcn_s_barrier();
  __builtin_amdgcn_sched_barrier(0);

  for (int ib = 0; ib < 16; ib++) {
    if (ib > 0) {
      __builtin_amdgcn_s_barrier();
      __builtin_amdgcn_sched_barrier(0);
    }
    if (ib + 1 < 16) stageX(ib + 1, (ib + 1) & 1);
    __builtin_amdgcn_sched_barrier(0);
    const f16* xb = smem + (ib & 1) * 17408;
    readA(xb, 0, afr[0]);
    #pragma unroll
    for (int wt = 0; wt < 16; wt++) {
      if (wt < 15) readA(xb, wt + 1, afr[(wt + 1) & 1]);
      const int kt = ib * 16 + wt;
      if (kt + 1 < 256) loadB(kt + 1, bfr[(wt & 1) ^ 1]);
      if (wt == 15 && wp == 0) loadV(ib, vf);
      __builtin_amdgcn_s_setprio(1);
      #pragma unroll
      for (int i = 0; i < 4; i++)
        #pragma unroll
        for (int j = 0; j < 4; j++)
          acc[i][j] = __builtin_amdgcn_mfma_f32_16x16x32_f16(
              afr[wt & 1][i], bfr[wt & 1][2 * j], acc[i][j], 0, 0, 0);
      #pragma unroll
      for (int i = 0; i < 4; i++)
        #pragma unroll
        for (int j = 0; j < 4; j++)
          acc[i][j] = __builtin_amdgcn_mfma_f32_16x16x32_f16(
              afr[wt & 1][4 + i], bfr[wt & 1][2 * j + 1], acc[i][j], 0, 0, 0);
      __builtin_amdgcn_s_setprio(0);
      if (wt == 15 && wp == 0) {
        // v-projection: afr[1] holds tap-15 fragments = x[t0+row] (K-slice ib)
        __builtin_amdgcn_s_setprio(1);
        #pragma unroll
        for (int i = 0; i < 4; i++)
          #pragma unroll
          for (int j = 0; j < 4; j++)
            vacc[i][j] = __builtin_amdgcn_mfma_f32_16x16x32_f16(
                afr[1][i], vf[2 * j], vacc[i][j], 0, 0, 0);
        #pragma unroll
        for (int i = 0; i < 4; i++)
          #pragma unroll
          for (int j = 0; j < 4; j++)
            vacc[i][j] = __builtin_amdgcn_mfma_f32_16x16x32_f16(
                afr[1][4 + i], vf[2 * j + 1], vacc[i][j], 0, 0, 0);
        __builtin_amdgcn_s_setprio(0);
      }
    }
  }

  // ---- epilogue: bias add + direct (b,h,t,d) write. C/D: col=lane&15, row=(lane>>4)*4+reg ----
  const int crow = (lane >> 4) << 2;
  const int ccol = lane & 15;
  const int hh = n0 >> 6;
  const float* bias = wp ? bk : bq;
  f16* outp = wp ? ok : oq;
  #pragma unroll
  for (int j = 0; j < 4; j++) {
    const int col = n0 + j * 16 + ccol;
    const float bvl = bias[col];
    const int d = (j << 4) + ccol;
    #pragma unroll
    for (int i = 0; i < 4; i++) {
      #pragma unroll
      for (int r = 0; r < 4; r++) {
        const int row = m0 + wq * 64 + i * 16 + crow + r;
        const int b = row >> 11, t = row & (TSEQ - 1);
        outp[((size_t)(b * 16 + hh) * TSEQ + t) * 64 + d] = (f16)(acc[i][j][r] + bvl);
      }
    }
  }
  if (wp == 0) {
    #pragma unroll
    for (int j = 0; j < 4; j++) {
      const int col = n0 + j * 16 + ccol;
      const float bvl = bv[col];
      const int d = (j << 4) + ccol;
      #pragma unroll
      for (int i = 0; i < 4; i++) {
        #pragma unroll
        for (int r = 0; r < 4; r++) {
          const int row = m0 + wq * 64 + i * 16 + crow + r;
          const int b = row >> 11, t = row & (TSEQ - 1);
          ov[((size_t)(b * 16 + hh) * TSEQ + t) * 64 + d] = (f16)(vacc[i][j][r] + bvl);
        }
      }
    }
  }
}

// ---------------- small GEMM (K=1024): p-proj ----------------
// Double-buffered (T3 minimum 2-phase). MODE 1: fp32 out to (b,t,d) d_out.
template<int MODE>
__global__ __launch_bounds__(256, 2) void gemm_small(
    const f16* __restrict__ A, const f16* __restrict__ Bw,
    const float* __restrict__ bias, f16* __restrict__ oh, float* __restrict__ ofp)
{
  __shared__ f16 As[2][128 * 32];
  __shared__ f16 Bs[2][128 * 32];
  const int tid = threadIdx.x;
  const int lane = tid & 63;
  const int wid = tid >> 6;
  const int m0 = blockIdx.x * 128;
  const int n0 = blockIdx.y * 128;

  const int srow = lane >> 2;
  const int scg = ((lane & 3) ^ ((lane >> 3) & 3)) * 8;
  const int wm = wid & 1;
  const int wn = wid >> 1;

  f32x4 acc[4][4] = {};

  auto stage = [&](int kk, int buf) {
    if (wid < 2) {
      #pragma unroll
      for (int c = 0; c < 4; c++) {
        const int r = wid * 64 + c * 16 + srow;
        const void* g = (const void*)(A + (((size_t)(m0 + r)) << 10) + kk + scg);
        gload_lds16(g, (void*)&As[buf][(wid * 64 + c * 16) * 32]);
      }
    } else {
      #pragma unroll
      for (int c = 0; c < 4; c++) {
        const int r = (wid - 2) * 64 + c * 16 + srow;
        const void* g = (const void*)(Bw + (((size_t)(n0 + r)) << 10) + kk + scg);
        gload_lds16(g, (void*)&Bs[buf][((wid - 2) * 64 + c * 16) * 32]);
      }
    }
  };

  stage(0, 0);
  asm volatile("s_waitcnt vmcnt(0)" ::: "memory");
  __syncthreads();

  int buf = 0;
  for (int it = 0; it < 32; it++) {
    if (it + 1 < 32) stage((it + 1) * 32, buf ^ 1);
    const int koff = ((lane >> 4) ^ ((lane >> 1) & 3)) * 8;
    f16x8 af[4], bf[4];
    #pragma unroll
    for (int i = 0; i < 4; i++) {
      af[i] = *(const f16x8*)&As[buf][(wm * 64 + i * 16 + (lane & 15)) * 32 + koff];
      bf[i] = *(const f16x8*)&Bs[buf][(wn * 64 + i * 16 + (lane & 15)) * 32 + koff];
    }
    #pragma unroll
    for (int i = 0; i < 4; i++)
      #pragma unroll
      for (int j = 0; j < 4; j++)
        acc[i][j] = __builtin_amdgcn_mfma_f32_16x16x32_f16(af[i], bf[j], acc[i][j], 0, 0, 0);
    asm volatile("s_waitcnt vmcnt(0)" ::: "memory");
    __syncthreads();
    buf ^= 1;
  }

  const int crow = (lane >> 4) * 4;
  const int ccol = lane & 15;
  #pragma unroll
  for (int j = 0; j < 4; j++) {
    const int col = n0 + wn * 64 + j * 16 + ccol;
    const float bvl = bias[col];
    #pragma unroll
    for (int i = 0; i < 4; i++) {
      #pragma unroll
      for (int r = 0; r < 4; r++) {
        const int row = m0 + wm * 64 + i * 16 + crow + r;
        const float val = acc[i][j][r] + bvl;
        if (MODE == 1) {
          ofp[(size_t)row * DDIM + col] = val;
        } else {
          const int b = row >> 11, t = row & (TSEQ - 1);
          const int h = col >> 6, d = col & 63;
          oh[((size_t)(b * 16 + h) * TSEQ + t) * 64 + d] = (f16)val;
        }
      }
    }
  }
}

// ------- log-sparse scores, (b,h,t,d) layout, coalesced + fdot2 -------
__global__ __launch_bounds__(256) void score_k(const f16* __restrict__ qh,
                                               const f16* __restrict__ kh,
                                               float* __restrict__ scores) {
  const int bid = blockIdx.x;
  const int bh = bid >> 5, tc = bid & 31;
  const int tid = threadIdx.x;
  const int wave = tid >> 6, lane = tid & 63;
  const int tr = lane >> 3, dc = lane & 7;
  const size_t base = ((size_t)bh) << 17;
  const f16* qb = qh + base;
  const f16* kb = kh + base;

  #pragma unroll
  for (int p = 0; p < 2; p++) {
    const int t = tc * 64 + p * 32 + wave * 8 + tr;
    f16x8 qv = *(const f16x8*)(qb + (size_t)t * 64 + dc * 8);
    const f16x2* qp = (const f16x2*)&qv;
    #pragma unroll
    for (int e = 0; e < 8; e++) {
      const int ts = (t + (1 << e)) & (TSEQ - 1);
      f16x8 kv = *(const f16x8*)(kb + (size_t)ts * 64 + dc * 8);
      const f16x2* kp = (const f16x2*)&kv;
      float s = 0.f;
      #pragma unroll
      for (int j = 0; j < 4; j++) s = __builtin_amdgcn_fdot2(qp[j], kp[j], s, false);
      s += __shfl_xor(s, 1, 64);
      s += __shfl_xor(s, 2, 64);
      s += __shfl_xor(s, 4, 64);
      if (dc == 0) scores[((size_t)(bh * 8 + e) << 11) + t] = s * 0.125f;
    }
  }
}

// ---- in-place softmax over T per (b,h,e) row: 256 rows of 2048 ----
__global__ void softmax_k(float* __restrict__ scores) {
  __shared__ float red[4];
  int row = blockIdx.x;
  float* p = scores + ((size_t)row << 11);
  int tid = threadIdx.x;
  float v[8];
  float4 a = ((const float4*)p)[tid * 2];
  float4 b = ((const float4*)p)[tid * 2 + 1];
  v[0] = a.x; v[1] = a.y; v[2] = a.z; v[3] = a.w;
  v[4] = b.x; v[5] = b.y; v[6] = b.z; v[7] = b.w;
  float m = v[0];
  #pragma unroll
  for (int j = 1; j < 8; j++) m = fmaxf(m, v[j]);
  for (int o = 32; o > 0; o >>= 1) m = fmaxf(m, __shfl_xor(m, o, 64));
  if ((tid & 63) == 0) red[tid >> 6] = m;
  __syncthreads();
  m = fmaxf(fmaxf(red[0], red[1]), fmaxf(red[2], red[3]));
  __syncthreads();
  float s = 0.f;
  #pragma unroll
  for (int j = 0; j < 8; j++) { v[j] = __expf(v[j] - m); s += v[j]; }
  for (int o = 32; o > 0; o >>= 1) s += __shfl_xor(s, o, 64);
  if ((tid & 63) == 0) red[tid >> 6] = s;
  __syncthreads();
  s = (red[0] + red[1]) + (red[2] + red[3]);
  float inv = 1.0f / s;
  float4 o1 = make_float4(v[0] * inv, v[1] * inv, v[2] * inv, v[3] * inv);
  float4 o2 = make_float4(v[4] * inv, v[5] * inv, v[6] * inv, v[7] * inv);
  ((float4*)p)[tid * 2] = o1;
  ((float4*)p)[tid * 2 + 1] = o2;
}

// ------- local windowed attention + log-sparse combine -> outh (b,t,d) -------
__global__ __launch_bounds__(256) void attn_out_k(
    const f16* __restrict__ qh, const f16* __restrict__ kh, const f16* __restrict__ vh,
    const float* __restrict__ alpha, f16* __restrict__ outh)
{
  __shared__ f16 qL[64 * 64];
  __shared__ f16 kL[80 * 64];
  __shared__ f16 vL[208 * 64];
  __shared__ float scL[64 * 16];
  __shared__ float aL[8 * 64];
  const int bh = blockIdx.x, tc = blockIdx.y;
  const int t0 = tc * 64;
  const int tid = threadIdx.x;
  const size_t base = ((size_t)bh) << 17;

  for (int idx = tid; idx < 64 * 8; idx += 256) {
    int r = idx >> 3, c = idx & 7, sl = c ^ (r & 7);
    *(uint4*)&qL[r * 64 + sl * 8] = *(const uint4*)(qh + base + (size_t)(t0 + r) * 64 + c * 8);
  }
  for (int idx = tid; idx < 79 * 8; idx += 256) {
    int r = idx >> 3, c = idx & 7, sl = c ^ (r & 7);
    int g = t0 - 15 + r;
    uint4 val = (g < 0) ? make_uint4(0, 0, 0, 0)
                        : *(const uint4*)(kh + base + (size_t)g * 64 + c * 8);
    *(uint4*)&kL[r * 64 + sl * 8] = val;
  }
  for (int idx = tid; idx < 207 * 8; idx += 256) {
    int r = idx >> 3, c = idx & 7, sl = c ^ (r & 7);
    int g = t0 - 15 + r;
    uint4 val;
    if (g < 0) val = make_uint4(0, 0, 0, 0);
    else {
      if (g >= TSEQ) g -= TSEQ;
      val = *(const uint4*)(vh + base + (size_t)g * 64 + c * 8);
    }
    *(uint4*)&vL[r * 64 + sl * 8] = val;
  }
  for (int idx = tid; idx < 512; idx += 256) {
    int e = idx >> 6, i = idx & 63;
    aL[e * 64 + i] = alpha[((size_t)(bh * 8 + e) << 11) + t0 + i];
  }
  __syncthreads();

  {
    const int tl = tid & 63;
    const int wg = tid >> 6;
    f16x8 qv[8];
    #pragma unroll
    for (int c = 0; c < 8; c++) qv[c] = *(const f16x8*)&qL[tl * 64 + ((c ^ (tl & 7)) * 8)];
    const f16x2* qp = (const f16x2*)&qv[0];
    #pragma unroll
    for (int wi = 0; wi < 4; wi++) {
      const int w = wg * 4 + wi;
      const int r = tl + w;
      float s = 0.f;
      #pragma unroll
      for (int c = 0; c < 8; c++) {
        f16x8 kv = *(const f16x8*)&kL[r * 64 + ((c ^ (r & 7)) * 8)];
        const f16x2* kp = (const f16x2*)&kv;
        #pragma unroll
        for (int j = 0; j < 4; j++) s = __builtin_amdgcn_fdot2(qp[c * 4 + j], kp[j], s, false);
      }
      scL[tl * 16 + w] = s * 0.125f;
    }
  }
  __syncthreads();

  if (tid < 64) {
    float sc[16];
    float m = -1e30f;
    #pragma unroll
    for (int w = 0; w < 16; w++) { sc[w] = scL[tid * 16 + w]; m = fmaxf(m, sc[w]); }
    float sum = 0.f;
    #pragma unroll
    for (int w = 0; w < 16; w++) { sc[w] = __expf(sc[w] - m); sum += sc[w]; }
    float inv = 1.0f / sum;
    #pragma unroll
    for (int w = 0; w < 16; w++) scL[tid * 16 + w] = sc[w] * inv;
  }
  __syncthreads();

  {
    const int tl = tid >> 2;
    const int qd = tid & 3;
    float accv[16] = {};
    #pragma unroll
    for (int w = 0; w < 16; w++) {
      const float pw_ = scL[tl * 16 + w];
      const int r = tl + w;
      #pragma unroll
      for (int c2 = 0; c2 < 2; c2++) {
        const int c = qd * 2 + c2;
        f16x8 v = *(const f16x8*)&vL[r * 64 + ((c ^ (r & 7)) * 8)];
        #pragma unroll
        for (int j = 0; j < 8; j++) accv[c2 * 8 + j] += pw_ * (float)v[j];
      }
    }
    #pragma unroll
    for (int e = 0; e < 8; e++) {
      const float a = aL[e * 64 + tl];
      const int r = tl + 15 + (1 << e);
      #pragma unroll
      for (int c2 = 0; c2 < 2; c2++) {
        const int c = qd * 2 + c2;
        f16x8 v = *(const f16x8*)&vL[r * 64 + ((c ^ (r & 7)) * 8)];
        #pragma unroll
        for (int j = 0; j < 8; j++) accv[c2 * 8 + j] += a * (float)v[j];
      }
    }
    const int b = bh >> 4, h = bh & 15;
    f16* orow = outh + ((size_t)(b * TSEQ + t0 + tl)) * DDIM + h * 64 + qd * 16;
    #pragma unroll
    for (int c2 = 0; c2 < 2; c2++) {
      f16x8 v;
      #pragma unroll
      for (int j = 0; j < 8; j++) v[j] = (f16)accv[c2 * 8 + j];
      *(f16x8*)(orow + c2 * 8) = v;
    }
  }
}

extern "C" void kernel_launch(void* const* d_in, const int* in_sizes, int n_in,
                              void* d_out, int out_size, void* d_ws, size_t ws_size,
                              hipStream_t stream) {
  (void)in_sizes; (void)n_in; (void)out_size; (void)ws_size;
  const float* x   = (const float*)d_in[0];
  const float* q_w = (const float*)d_in[1];
  const float* q_b = (const float*)d_in[2];
  const float* k_w = (const float*)d_in[3];
  const float* k_b = (const float*)d_in[4];
  const float* v_w = (const float*)d_in[5];
  const float* v_b = (const float*)d_in[6];
  const float* p_w = (const float*)d_in[7];
  const float* p_b = (const float*)d_in[8];
  float* out = (float*)d_out;

  char* ws = (char*)d_ws;
  f16* xh      = (f16*)(ws);                 //  8.4 MB (b,t,d)
  f16* qwh     = (f16*)(ws + 8388608);       // 33.6 MB fragment-ordered Wfq
  f16* kwh     = (f16*)(ws + 41943040);      // 33.6 MB fragment-ordered Wfk
  f16* vwh     = (f16*)(ws + 75497472);      //  2.1 MB fragment-ordered Wfv
  f16* pwh     = (f16*)(ws + 77594624);      //  2.1 MB flat [o][k]
  f16* qh      = (f16*)(ws + 79691776);      //  8.4 MB (b,h,t,d)
  f16* kh      = (f16*)(ws + 88080384);      //  8.4 MB (b,h,t,d)
  f16* vh      = (f16*)(ws + 96468992);      //  8.4 MB (b,h,t,d)
  f16* outh    = (f16*)(ws + 104857600);     //  8.4 MB (b,t,d)
  float* alpha = (float*)(ws + 113246208);   //  2.1 MB (B*H*E, T)
  // total 115.4 MB

  static int s_attr_done = 0;
  if (!s_attr_done) {
    hipFuncSetAttribute((const void*)gemm_qk8,
                        hipFuncAttributeMaxDynamicSharedMemorySize, 69632);
    hipFuncSetAttribute((const void*)cvt_w_frag,
                        hipFuncAttributeMaxDynamicSharedMemorySize, 66560);
    s_attr_done = 1;
  }

  cvt_all<<<5120, 256, 0, stream>>>(x, p_w, xh, pwh);
  cvt_vw_frag<<<256, 256, 0, stream>>>(v_w, vwh);
  cvt_w_frag<<<1024, 256, 66560, stream>>>(q_w, k_w, qwh, kwh);

  // fused q+k+v GEMM: A-slab LDS (68KB dyn), B/V direct to regs, 256 blocks = 1/CU
  gemm_qk8<<<dim3(16, 16), 512, 69632, stream>>>(xh, qwh, kwh, vwh,
                                                 q_b, k_b, v_b, qh, kh, vh);

  score_k<<<1024, 256, 0, stream>>>(qh, kh, alpha);
  softmax_k<<<256, 256, 0, stream>>>(alpha);
  attn_out_k<<<dim3(32, 32), 256, 0, stream>>>(qh, kh, vh, alpha, outh);

  // final projection -> fp32 d_out
  gemm_small<1><<<dim3(32, 8), 256, 0, stream>>>(outh, pwh, p_b, nullptr, out);
}

// Round 10
// 475.086 us; speedup vs baseline: 1.3031x; 1.3031x over previous
//
#include <hip/hip_runtime.h>
#include <cstdint>
#include <cstddef>

#define TSEQ 2048
#define DDIM 1024

typedef _Float16 f16;
typedef _Float16 f16x2 __attribute__((ext_vector_type(2)));
typedef _Float16 f16x4 __attribute__((ext_vector_type(4)));
typedef _Float16 f16x8 __attribute__((ext_vector_type(8)));
typedef float f32x4 __attribute__((ext_vector_type(4)));

// q,k,v live in (b,h,t,d) layout: ((b*16+h)*2048 + t)*64 + d.
// Conv weights for gemm_qk8 live in MFMA-FRAGMENT order:
//   Wf[nb][kt][f=j*2+s][lane][8] : value = W[o=nb*64+j*16+(lane&15)]
//                                         [i=(kt>>4)*64+s*32+(lane>>4)*8+c][tap w=kt&15]
// K-order is (i-block, tap) so 16 consecutive kt share the same x-rows (shifted).
// REGISTER-BUDGET LESSON (r4/r5/r8/r9): the allocator pins this kernel at 128 VGPR;
// any structure needing more live state (A-reg dbuf, fused v-proj) spills to scratch
// (WRITE_SIZE blowup). The r3 body below (acc 64 + bfr 64 + transient af 32 = ~116)
// is the measured optimum: 211 us, MfmaUtil 67.6%.

__device__ __align__(16) static const unsigned char g_zero16[16] = {};

__device__ __forceinline__ void gload_lds16(const void* g, void* l) {
  __builtin_amdgcn_global_load_lds(
      (const __attribute__((address_space(1))) void*)g,
      (__attribute__((address_space(3))) void*)l, 16, 0, 0);
}

// ------------- fused fp32->fp16 converts (x, v_w, p_w) -------------
__global__ void cvt_all(const float* __restrict__ x, const float* __restrict__ vw,
                        const float* __restrict__ pw,
                        f16* __restrict__ xh, f16* __restrict__ vwh, f16* __restrict__ pwh) {
  int b = blockIdx.x;
  const float* src; f16* dst; int i;
  if (b < 4096)      { src = x;  dst = xh;  i = b * 256 + threadIdx.x; }
  else if (b < 5120) { src = vw; dst = vwh; i = (b - 4096) * 256 + threadIdx.x; }
  else               { src = pw; dst = pwh; i = (b - 5120) * 256 + threadIdx.x; }
  float4 v = ((const float4*)src)[i];
  f16x4 h = { (f16)v.x, (f16)v.y, (f16)v.z, (f16)v.w };
  ((f16x4*)dst)[i] = h;
}

// ------- conv weights w[o][i][16] fp32 -> fragment-ordered Wf, coalesced both ends -------
// 1024 blocks = [proj2][nb16][j4][ic8]; block owns 16 o-rows (one j-frag) x 128 i x 16 w.
__global__ __launch_bounds__(256) void cvt_w_frag(const float* __restrict__ qw,
                                                  const float* __restrict__ kw,
                                                  f16* __restrict__ qd, f16* __restrict__ kd) {
  extern __shared__ f16 wt_lds[];    // 16*16*130 f16 = 66560 B
  const int bid = blockIdx.x;
  const int proj = bid >> 9;
  const int nb = (bid >> 5) & 15;
  const int j = (bid >> 3) & 3;
  const int ic = bid & 7;
  const float* src = proj ? kw : qw;
  f16* dst = proj ? kd : qd;
  const int o_base = nb * 64 + j * 16;
  const int tid = threadIdx.x;
  const int lane = tid & 63;
  const int wv = tid >> 6;

  #pragma unroll
  for (int p = 0; p < 32; p++) {
    const int gidx = p * 256 + tid;         // 0..8191
    const int o_r = gidx >> 9;              // 0..15
    const int i_r = (gidx >> 2) & 127;      // 0..127
    const int wq2 = gidx & 3;               // w-quad
    float4 v = *(const float4*)(src + (size_t)(o_base + o_r) * 16384 +
                                (size_t)(ic * 128 + i_r) * 16 + wq2 * 4);
    const int g = i_r >> 3;
    const int gp = (g & 8) | ((g & 7) ^ (o_r & 7));
    const int ip = gp * 8 + (i_r & 7);
    f16* t0 = wt_lds + ((wq2 * 4) * 16 + o_r) * 130 + ip;
    t0[0]    = (f16)v.x;
    t0[2080] = (f16)v.y;
    t0[4160] = (f16)v.z;
    t0[6240] = (f16)v.w;
  }
  __syncthreads();

  const int o = lane & 15;
  const int lhi = lane >> 4;
  #pragma unroll
  for (int u4 = 0; u4 < 16; u4++) {
    const int u = u4 * 4 + wv;              // 0..63
    const int w = u >> 2, ih = (u >> 1) & 1, s = u & 1;
    const int gl = ih * 8 + s * 4 + lhi;    // linear granule 0..15
    const int gp = (gl & 8) | ((gl & 7) ^ (o & 7));
    f16x8 val = *(const f16x8*)&wt_lds[(w * 16 + o) * 130 + gp * 8];
    const size_t unit = ((size_t)(nb * 256 + (ic * 2 + ih) * 16 + w) * 8) + j * 2 + s;
    *(f16x8*)(dst + unit * 512 + lane * 8) = val;
  }
}

// ------------- fused q+k conv-GEMM: A-slab in LDS, B direct global->VGPR -------------
// EXACT round-3 body (measured 211 us / VGPR 116). BM=256, BK=64, K-order (i-block,
// tap). Per i-block: stage 271-row x 64-ch slab once (34 KB), sweep 16 taps reading
// A-frags from the resident slab; B-frags double-buffered in registers. Barrier only
// at slab swap. A(ib)-completeness: each wave's per-tile B-reg vmcnt wait drains the
// older stageX (vmcnt is in-order) before the boundary barrier.
__global__ __launch_bounds__(512, 1) void gemm_qk8(
    const f16* __restrict__ xh,
    const f16* __restrict__ Wfq, const f16* __restrict__ Wfk,
    const float* __restrict__ bq, const float* __restrict__ bk,
    f16* __restrict__ oq, f16* __restrict__ ok)
{
  extern __shared__ __align__(16) f16 smem[];   // 2 * 17408 f16 = 68 KB
  const int tid = threadIdx.x;
  const int lane = tid & 63;
  const int wid = tid >> 6;          // 0..7
  const int wq = wid >> 1;           // M-quarter 0..3 (64 rows each)
  const int wp = wid & 1;            // 0 = q projection, 1 = k projection

  // XCD-bijective remap: each XCD owns 2 n-columns (weights fetched once per XCD)
  const int flat = blockIdx.y * 16 + blockIdx.x;
  const int xcd = flat & 7;
  const int idx = flat >> 3;                  // 0..31
  const int nblk = xcd * 2 + (idx >> 4);
  const int mblk = idx & 15;
  const int m0 = mblk * 256;
  const int n0 = nblk * 64;
  const int bT = m0 & ~(TSEQ - 1);
  const int t0 = m0 & (TSEQ - 1);

  // staging swizzle: lane l writes LDS slot (l&7); global chunk = (l&7)^(row&7)
  const int srow = lane >> 3;
  const int chunk8 = (((lane & 7) ^ (srow & 7)) << 3);

  const f16* Wf = wp ? Wfk : Wfq;
  const f16* wbase = Wf + ((size_t)nblk << 20) + lane * 8;   // nblk * 1048576 f16

  f32x4 acc[4][4] = {};
  f16x8 bfr[2][8];

  // stage the 271-row x 64-channel slab for i-block ib2 (34 groups of 8 rows)
  auto stageX = [&](int ib2, int bufp) {
    f16* sb = smem + bufp * 17408;
    const int ic = ib2 * 64 + chunk8;
    #pragma unroll
    for (int c = 0; c < 5; c++) {
      const int g = c * 8 + wid;
      if (g < 34) {
        const int srcT = t0 + g * 8 + srow - 15;
        const void* gp = (srcT >= 0)
            ? (const void*)(xh + (((size_t)(bT + srcT)) << 10) + ic)
            : (const void*)g_zero16;
        gload_lds16(gp, (void*)&sb[g * 512]);
      }
    }
  };

  auto loadB = [&](int kt, f16x8* bf) {
    const f16* p = wbase + ((size_t)kt << 12);   // kt * 4096 f16
    #pragma unroll
    for (int f = 0; f < 8; f++)
      bf[f] = *(const f16x8*)(p + f * 512);
  };

  // prologue
  stageX(0, 0);
  loadB(0, bfr[0]);
  asm volatile("s_waitcnt vmcnt(0)" ::: "memory");
  __builtin_amdgcn_s_barrier();
  __builtin_amdgcn_sched_barrier(0);

  for (int ib = 0; ib < 16; ib++) {
    if (ib > 0) {
      __builtin_amdgcn_s_barrier();
      __builtin_amdgcn_sched_barrier(0);
    }
    if (ib + 1 < 16) stageX(ib + 1, (ib + 1) & 1);
    __builtin_amdgcn_sched_barrier(0);
    const f16* xb = smem + (ib & 1) * 17408;
    #pragma unroll
    for (int wt = 0; wt < 16; wt++) {
      const int kt = ib * 16 + wt;
      const int rx = ((lane & 7) + wt) & 7;              // (row+tap)&7
      const int sl0 = (((lane >> 4)) ^ rx) << 3;         // slice 0 slot
      const int sl1 = (((lane >> 4) + 4) ^ rx) << 3;     // slice 1 slot
      f16x8 af[8];
      #pragma unroll
      for (int i = 0; i < 4; i++) {
        const int row = wq * 64 + i * 16 + (lane & 15) + wt;
        af[i]     = *(const f16x8*)&xb[row * 64 + sl0];
        af[4 + i] = *(const f16x8*)&xb[row * 64 + sl1];
      }
      if (kt + 1 < 256) loadB(kt + 1, bfr[(wt & 1) ^ 1]);
      __builtin_amdgcn_s_setprio(1);
      #pragma unroll
      for (int i = 0; i < 4; i++)
        #pragma unroll
        for (int j = 0; j < 4; j++)
          acc[i][j] = __builtin_amdgcn_mfma_f32_16x16x32_f16(
              af[i], bfr[wt & 1][2 * j], acc[i][j], 0, 0, 0);
      #pragma unroll
      for (int i = 0; i < 4; i++)
        #pragma unroll
        for (int j = 0; j < 4; j++)
          acc[i][j] = __builtin_amdgcn_mfma_f32_16x16x32_f16(
              af[4 + i], bfr[wt & 1][2 * j + 1], acc[i][j], 0, 0, 0);
      __builtin_amdgcn_s_setprio(0);
    }
  }

  // ---- epilogue: bias add + direct (b,h,t,d) write. C/D: col=lane&15, row=(lane>>4)*4+reg ----
  const int crow = (lane >> 4) << 2;
  const int ccol = lane & 15;
  const int hh = n0 >> 6;
  const float* bias = wp ? bk : bq;
  f16* outp = wp ? ok : oq;
  #pragma unroll
  for (int j = 0; j < 4; j++) {
    const int col = n0 + j * 16 + ccol;
    const float bvl = bias[col];
    const int d = (j << 4) + ccol;
    #pragma unroll
    for (int i = 0; i < 4; i++) {
      #pragma unroll
      for (int r = 0; r < 4; r++) {
        const int row = m0 + wq * 64 + i * 16 + crow + r;
        const int b = row >> 11, t = row & (TSEQ - 1);
        outp[((size_t)(b * 16 + hh) * TSEQ + t) * 64 + d] = (f16)(acc[i][j][r] + bvl);
      }
    }
  }
}

// ---------------- small GEMM (K=1024): v-proj / p-proj ----------------
// Double-buffered (T3 minimum 2-phase): prologue stage; per iter {stage next ->
// ds_read cur -> MFMA -> vmcnt(0)+barrier}.
// MODE 0: fp16 out to (b,h,t,d) layout (v). MODE 1: fp32 out to (b,t,d) d_out (p).
template<int MODE>
__global__ __launch_bounds__(256, 2) void gemm_small(
    const f16* __restrict__ A, const f16* __restrict__ Bw,
    const float* __restrict__ bias, f16* __restrict__ oh, float* __restrict__ ofp)
{
  __shared__ f16 As[2][128 * 32];
  __shared__ f16 Bs[2][128 * 32];
  const int tid = threadIdx.x;
  const int lane = tid & 63;
  const int wid = tid >> 6;
  const int m0 = blockIdx.x * 128;
  const int n0 = blockIdx.y * 128;

  const int srow = lane >> 2;
  const int scg = ((lane & 3) ^ ((lane >> 3) & 3)) * 8;
  const int wm = wid & 1;
  const int wn = wid >> 1;

  f32x4 acc[4][4] = {};

  auto stage = [&](int kk, int buf) {
    if (wid < 2) {
      #pragma unroll
      for (int c = 0; c < 4; c++) {
        const int r = wid * 64 + c * 16 + srow;
        const void* g = (const void*)(A + (((size_t)(m0 + r)) << 10) + kk + scg);
        gload_lds16(g, (void*)&As[buf][(wid * 64 + c * 16) * 32]);
      }
    } else {
      #pragma unroll
      for (int c = 0; c < 4; c++) {
        const int r = (wid - 2) * 64 + c * 16 + srow;
        const void* g = (const void*)(Bw + (((size_t)(n0 + r)) << 10) + kk + scg);
        gload_lds16(g, (void*)&Bs[buf][((wid - 2) * 64 + c * 16) * 32]);
      }
    }
  };

  stage(0, 0);
  asm volatile("s_waitcnt vmcnt(0)" ::: "memory");
  __syncthreads();

  int buf = 0;
  for (int it = 0; it < 32; it++) {
    if (it + 1 < 32) stage((it + 1) * 32, buf ^ 1);
    const int koff = ((lane >> 4) ^ ((lane >> 1) & 3)) * 8;
    f16x8 af[4], bf[4];
    #pragma unroll
    for (int i = 0; i < 4; i++) {
      af[i] = *(const f16x8*)&As[buf][(wm * 64 + i * 16 + (lane & 15)) * 32 + koff];
      bf[i] = *(const f16x8*)&Bs[buf][(wn * 64 + i * 16 + (lane & 15)) * 32 + koff];
    }
    #pragma unroll
    for (int i = 0; i < 4; i++)
      #pragma unroll
      for (int j = 0; j < 4; j++)
        acc[i][j] = __builtin_amdgcn_mfma_f32_16x16x32_f16(af[i], bf[j], acc[i][j], 0, 0, 0);
    asm volatile("s_waitcnt vmcnt(0)" ::: "memory");
    __syncthreads();
    buf ^= 1;
  }

  const int crow = (lane >> 4) * 4;
  const int ccol = lane & 15;
  #pragma unroll
  for (int j = 0; j < 4; j++) {
    const int col = n0 + wn * 64 + j * 16 + ccol;
    const float bvl = bias[col];
    #pragma unroll
    for (int i = 0; i < 4; i++) {
      #pragma unroll
      for (int r = 0; r < 4; r++) {
        const int row = m0 + wm * 64 + i * 16 + crow + r;
        const float val = acc[i][j][r] + bvl;
        if (MODE == 1) {
          ofp[(size_t)row * DDIM + col] = val;
        } else {
          const int b = row >> 11, t = row & (TSEQ - 1);
          const int h = col >> 6, d = col & 63;
          oh[((size_t)(b * 16 + h) * TSEQ + t) * 64 + d] = (f16)val;
        }
      }
    }
  }
}

// ------- log-sparse scores, (b,h,t,d) layout, coalesced + fdot2 -------
__global__ __launch_bounds__(256) void score_k(const f16* __restrict__ qh,
                                               const f16* __restrict__ kh,
                                               float* __restrict__ scores) {
  const int bid = blockIdx.x;
  const int bh = bid >> 5, tc = bid & 31;
  const int tid = threadIdx.x;
  const int wave = tid >> 6, lane = tid & 63;
  const int tr = lane >> 3, dc = lane & 7;
  const size_t base = ((size_t)bh) << 17;
  const f16* qb = qh + base;
  const f16* kb = kh + base;

  #pragma unroll
  for (int p = 0; p < 2; p++) {
    const int t = tc * 64 + p * 32 + wave * 8 + tr;
    f16x8 qv = *(const f16x8*)(qb + (size_t)t * 64 + dc * 8);
    const f16x2* qp = (const f16x2*)&qv;
    #pragma unroll
    for (int e = 0; e < 8; e++) {
      const int ts = (t + (1 << e)) & (TSEQ - 1);
      f16x8 kv = *(const f16x8*)(kb + (size_t)ts * 64 + dc * 8);
      const f16x2* kp = (const f16x2*)&kv;
      float s = 0.f;
      #pragma unroll
      for (int j = 0; j < 4; j++) s = __builtin_amdgcn_fdot2(qp[j], kp[j], s, false);
      s += __shfl_xor(s, 1, 64);
      s += __shfl_xor(s, 2, 64);
      s += __shfl_xor(s, 4, 64);
      if (dc == 0) scores[((size_t)(bh * 8 + e) << 11) + t] = s * 0.125f;
    }
  }
}

// ---- in-place softmax over T per (b,h,e) row: 256 rows of 2048 ----
__global__ void softmax_k(float* __restrict__ scores) {
  __shared__ float red[4];
  int row = blockIdx.x;
  float* p = scores + ((size_t)row << 11);
  int tid = threadIdx.x;
  float v[8];
  float4 a = ((const float4*)p)[tid * 2];
  float4 b = ((const float4*)p)[tid * 2 + 1];
  v[0] = a.x; v[1] = a.y; v[2] = a.z; v[3] = a.w;
  v[4] = b.x; v[5] = b.y; v[6] = b.z; v[7] = b.w;
  float m = v[0];
  #pragma unroll
  for (int j = 1; j < 8; j++) m = fmaxf(m, v[j]);
  for (int o = 32; o > 0; o >>= 1) m = fmaxf(m, __shfl_xor(m, o, 64));
  if ((tid & 63) == 0) red[tid >> 6] = m;
  __syncthreads();
  m = fmaxf(fmaxf(red[0], red[1]), fmaxf(red[2], red[3]));
  __syncthreads();
  float s = 0.f;
  #pragma unroll
  for (int j = 0; j < 8; j++) { v[j] = __expf(v[j] - m); s += v[j]; }
  for (int o = 32; o > 0; o >>= 1) s += __shfl_xor(s, o, 64);
  if ((tid & 63) == 0) red[tid >> 6] = s;
  __syncthreads();
  s = (red[0] + red[1]) + (red[2] + red[3]);
  float inv = 1.0f / s;
  float4 o1 = make_float4(v[0] * inv, v[1] * inv, v[2] * inv, v[3] * inv);
  float4 o2 = make_float4(v[4] * inv, v[5] * inv, v[6] * inv, v[7] * inv);
  ((float4*)p)[tid * 2] = o1;
  ((float4*)p)[tid * 2 + 1] = o2;
}

// ------- local windowed attention + log-sparse combine -> outh (b,t,d) -------
__global__ __launch_bounds__(256) void attn_out_k(
    const f16* __restrict__ qh, const f16* __restrict__ kh, const f16* __restrict__ vh,
    const float* __restrict__ alpha, f16* __restrict__ outh)
{
  __shared__ f16 qL[64 * 64];
  __shared__ f16 kL[80 * 64];
  __shared__ f16 vL[208 * 64];
  __shared__ float scL[64 * 16];
  __shared__ float aL[8 * 64];
  const int bh = blockIdx.x, tc = blockIdx.y;
  const int t0 = tc * 64;
  const int tid = threadIdx.x;
  const size_t base = ((size_t)bh) << 17;

  for (int idx = tid; idx < 64 * 8; idx += 256) {
    int r = idx >> 3, c = idx & 7, sl = c ^ (r & 7);
    *(uint4*)&qL[r * 64 + sl * 8] = *(const uint4*)(qh + base + (size_t)(t0 + r) * 64 + c * 8);
  }
  for (int idx = tid; idx < 79 * 8; idx += 256) {
    int r = idx >> 3, c = idx & 7, sl = c ^ (r & 7);
    int g = t0 - 15 + r;
    uint4 val = (g < 0) ? make_uint4(0, 0, 0, 0)
                        : *(const uint4*)(kh + base + (size_t)g * 64 + c * 8);
    *(uint4*)&kL[r * 64 + sl * 8] = val;
  }
  for (int idx = tid; idx < 207 * 8; idx += 256) {
    int r = idx >> 3, c = idx & 7, sl = c ^ (r & 7);
    int g = t0 - 15 + r;
    uint4 val;
    if (g < 0) val = make_uint4(0, 0, 0, 0);
    else {
      if (g >= TSEQ) g -= TSEQ;
      val = *(const uint4*)(vh + base + (size_t)g * 64 + c * 8);
    }
    *(uint4*)&vL[r * 64 + sl * 8] = val;
  }
  for (int idx = tid; idx < 512; idx += 256) {
    int e = idx >> 6, i = idx & 63;
    aL[e * 64 + i] = alpha[((size_t)(bh * 8 + e) << 11) + t0 + i];
  }
  __syncthreads();

  {
    const int tl = tid & 63;
    const int wg = tid >> 6;
    f16x8 qv[8];
    #pragma unroll
    for (int c = 0; c < 8; c++) qv[c] = *(const f16x8*)&qL[tl * 64 + ((c ^ (tl & 7)) * 8)];
    const f16x2* qp = (const f16x2*)&qv[0];
    #pragma unroll
    for (int wi = 0; wi < 4; wi++) {
      const int w = wg * 4 + wi;
      const int r = tl + w;
      float s = 0.f;
      #pragma unroll
      for (int c = 0; c < 8; c++) {
        f16x8 kv = *(const f16x8*)&kL[r * 64 + ((c ^ (r & 7)) * 8)];
        const f16x2* kp = (const f16x2*)&kv;
        #pragma unroll
        for (int j = 0; j < 4; j++) s = __builtin_amdgcn_fdot2(qp[c * 4 + j], kp[j], s, false);
      }
      scL[tl * 16 + w] = s * 0.125f;
    }
  }
  __syncthreads();

  if (tid < 64) {
    float sc[16];
    float m = -1e30f;
    #pragma unroll
    for (int w = 0; w < 16; w++) { sc[w] = scL[tid * 16 + w]; m = fmaxf(m, sc[w]); }
    float sum = 0.f;
    #pragma unroll
    for (int w = 0; w < 16; w++) { sc[w] = __expf(sc[w] - m); sum += sc[w]; }
    float inv = 1.0f / sum;
    #pragma unroll
    for (int w = 0; w < 16; w++) scL[tid * 16 + w] = sc[w] * inv;
  }
  __syncthreads();

  {
    const int tl = tid >> 2;
    const int qd = tid & 3;
    float accv[16] = {};
    #pragma unroll
    for (int w = 0; w < 16; w++) {
      const float pw_ = scL[tl * 16 + w];
      const int r = tl + w;
      #pragma unroll
      for (int c2 = 0; c2 < 2; c2++) {
        const int c = qd * 2 + c2;
        f16x8 v = *(const f16x8*)&vL[r * 64 + ((c ^ (r & 7)) * 8)];
        #pragma unroll
        for (int j = 0; j < 8; j++) accv[c2 * 8 + j] += pw_ * (float)v[j];
      }
    }
    #pragma unroll
    for (int e = 0; e < 8; e++) {
      const float a = aL[e * 64 + tl];
      const int r = tl + 15 + (1 << e);
      #pragma unroll
      for (int c2 = 0; c2 < 2; c2++) {
        const int c = qd * 2 + c2;
        f16x8 v = *(const f16x8*)&vL[r * 64 + ((c ^ (r & 7)) * 8)];
        #pragma unroll
        for (int j = 0; j < 8; j++) accv[c2 * 8 + j] += a * (float)v[j];
      }
    }
    const int b = bh >> 4, h = bh & 15;
    f16* orow = outh + ((size_t)(b * TSEQ + t0 + tl)) * DDIM + h * 64 + qd * 16;
    #pragma unroll
    for (int c2 = 0; c2 < 2; c2++) {
      f16x8 v;
      #pragma unroll
      for (int j = 0; j < 8; j++) v[j] = (f16)accv[c2 * 8 + j];
      *(f16x8*)(orow + c2 * 8) = v;
    }
  }
}

extern "C" void kernel_launch(void* const* d_in, const int* in_sizes, int n_in,
                              void* d_out, int out_size, void* d_ws, size_t ws_size,
                              hipStream_t stream) {
  (void)in_sizes; (void)n_in; (void)out_size; (void)ws_size;
  const float* x   = (const float*)d_in[0];
  const float* q_w = (const float*)d_in[1];
  const float* q_b = (const float*)d_in[2];
  const float* k_w = (const float*)d_in[3];
  const float* k_b = (const float*)d_in[4];
  const float* v_w = (const float*)d_in[5];
  const float* v_b = (const float*)d_in[6];
  const float* p_w = (const float*)d_in[7];
  const float* p_b = (const float*)d_in[8];
  float* out = (float*)d_out;

  char* ws = (char*)d_ws;
  f16* xh      = (f16*)(ws);                 //  8.4 MB (b,t,d)
  f16* qwh     = (f16*)(ws + 8388608);       // 33.6 MB fragment-ordered Wfq
  f16* kwh     = (f16*)(ws + 41943040);      // 33.6 MB fragment-ordered Wfk
  f16* vwh     = (f16*)(ws + 75497472);      //  2.1 MB flat [o][k]
  f16* pwh     = (f16*)(ws + 77594624);      //  2.1 MB flat [o][k]
  f16* qh      = (f16*)(ws + 79691776);      //  8.4 MB (b,h,t,d)
  f16* kh      = (f16*)(ws + 88080384);      //  8.4 MB (b,h,t,d)
  f16* vh      = (f16*)(ws + 96468992);      //  8.4 MB (b,h,t,d)
  f16* outh    = (f16*)(ws + 104857600);     //  8.4 MB (b,t,d)
  float* alpha = (float*)(ws + 113246208);   //  2.1 MB (B*H*E, T)
  // total 115.4 MB

  static int s_attr_done = 0;
  if (!s_attr_done) {
    hipFuncSetAttribute((const void*)gemm_qk8,
                        hipFuncAttributeMaxDynamicSharedMemorySize, 69632);
    hipFuncSetAttribute((const void*)cvt_w_frag,
                        hipFuncAttributeMaxDynamicSharedMemorySize, 66560);
    s_attr_done = 1;
  }

  cvt_all<<<6144, 256, 0, stream>>>(x, v_w, p_w, xh, vwh, pwh);
  cvt_w_frag<<<1024, 256, 66560, stream>>>(q_w, k_w, qwh, kwh);

  // fused q+k conv-GEMM: A-slab LDS (68KB dyn), B direct to regs, 256 blocks = 1/CU
  gemm_qk8<<<dim3(16, 16), 512, 69632, stream>>>(xh, qwh, kwh, q_b, k_b, qh, kh);
  // v projection
  gemm_small<0><<<dim3(32, 8), 256, 0, stream>>>(xh, vwh, v_b, vh, nullptr);

  score_k<<<1024, 256, 0, stream>>>(qh, kh, alpha);
  softmax_k<<<256, 256, 0, stream>>>(alpha);
  attn_out_k<<<dim3(32, 32), 256, 0, stream>>>(qh, kh, vh, alpha, outh);

  // final projection -> fp32 d_out
  gemm_small<1><<<dim3(32, 8), 256, 0, stream>>>(outh, pwh, p_b, nullptr, out);
}